// Round 10
// baseline (1175.753 us; speedup 1.0000x reference)
//
#include <hip/hip_runtime.h>

#define PTS    4096
#define TPB    256
#define PPB    32          // points per block (4 waves x 8 pts)
#define NSEG   8           // segments per point (in-wave, lane bits 3..5)
#define SEG    512         // candidates per segment
#define CAPP   44          // per-POINT collect capacity (E ~18, >8 sigma)
#define NCLOUD 16
#define NQUADS (NCLOUD * PTS / 4)
#define UMAX   0xFFFFFFFFu

typedef __attribute__((ext_vector_type(2))) float f32x2;

// insert key into unsorted top-N (s holds the N smallest seen, cmax = max of s)
template<int N>
__device__ __forceinline__ void insN(unsigned key, unsigned (&s)[N], unsigned &cmax) {
  if (key < cmax) {
    bool done = false;
#pragma unroll
    for (int i = 0; i < N; ++i) {
      bool c = (!done) && (s[i] == cmax);
      s[i] = c ? key : s[i];
      done = done || c;
    }
    cmax = s[0];
#pragma unroll
    for (int i = 1; i < N; ++i) cmax = (s[i] > cmax) ? s[i] : cmax;
  }
}

// AoS xyz quads -> quad-transposed {x0..x3, y0..y3, z0..z3} (48 B/quad, no pad)
__global__ void quad_pack(const float* __restrict__ x, float* __restrict__ ws) {
  const int g = blockIdx.x * blockDim.x + threadIdx.x;  // quad id
  const float* s = x + (size_t)g * 12;
  const float4 a = *(const float4*)(s + 0);  // x0 y0 z0 x1
  const float4 b = *(const float4*)(s + 4);  // y1 z1 x2 y2
  const float4 c = *(const float4*)(s + 8);  // z2 x3 y3 z3
  float* d = ws + (size_t)g * 12;
  *(float4*)(d + 0) = make_float4(a.x, a.w, b.z, c.y);
  *(float4*)(d + 4) = make_float4(a.y, b.x, b.w, c.z);
  *(float4*)(d + 8) = make_float4(a.z, b.y, c.x, c.w);
}

__global__ __launch_bounds__(TPB, 6) void knn_cov_c(const float* __restrict__ ws,
                                                    float* __restrict__ out) {
  __shared__ unsigned pbuf[PPB * CAPP];  // 5632 B: per-point compact candidates
  __shared__ unsigned pcnt[PPB];         // 128 B  (-> LDS-unconstrained occupancy)

  const int tid   = threadIdx.x;
  const int lane  = tid & 63;
  const int wid   = tid >> 6;
  const int pt    = wid * 8 + (lane & 7);   // point-in-block 0..31
  const int seg   = lane >> 3;              // segment 0..7 (lane bits 3,4,5)
  const int cloud = blockIdx.x >> 7;        // 128 chunks per cloud
  const int chunk = blockIdx.x & 127;
  const int p     = chunk * PPB + pt;       // in-cloud point index

  if (tid < PPB) pcnt[tid] = 0;

  const float* __restrict__ wc = ws + (size_t)cloud * (PTS / 4) * 12;

  const float* mp = wc + (size_t)(p >> 2) * 12;
  const int pe = p & 3;
  const float px = mp[0 + pe], py = mp[4 + pe], pz = mp[8 + pe];
  f32x2 vx; vx.x = px; vx.y = px;
  f32x2 vy; vy.x = py; vy.y = py;
  f32x2 vz; vz.x = pz; vz.y = pz;

  const int c0 = seg * SEG;
  const float* __restrict__ cp = wc + (size_t)(c0 >> 2) * 12;

  // ---- pass 1: 32 substream minima (16 packed pairs) over 512 candidates
  f32x2 m2[16];
#pragma unroll
  for (int j = 0; j < 16; ++j) { m2[j].x = 3.4e38f; m2[j].y = 3.4e38f; }
#pragma unroll 1
  for (int t0 = 0; t0 < SEG / 4; t0 += 8) {
#pragma unroll
    for (int q = 0; q < 8; ++q) {
      const float* qb = cp + (size_t)(t0 + q) * 12;
      const float4 X = *(const float4*)(qb + 0);
      const float4 Y = *(const float4*)(qb + 4);
      const float4 Z = *(const float4*)(qb + 8);
      f32x2 x01; x01.x = X.x; x01.y = X.y;
      f32x2 x23; x23.x = X.z; x23.y = X.w;
      f32x2 y01; y01.x = Y.x; y01.y = Y.y;
      f32x2 y23; y23.x = Y.z; y23.y = Y.w;
      f32x2 z01; z01.x = Z.x; z01.y = Z.y;
      f32x2 z23; z23.x = Z.z; z23.y = Z.w;
      const f32x2 dx0 = x01 - vx, dy0 = y01 - vy, dz0 = z01 - vz;
      const f32x2 dx1 = x23 - vx, dy1 = y23 - vy, dz1 = z23 - vz;
      const f32x2 d01 = dx0 * dx0 + dy0 * dy0 + dz0 * dz0;
      const f32x2 d23 = dx1 * dx1 + dy1 * dy1 + dz1 * dz1;
      m2[2 * q]     = __builtin_elementwise_min(m2[2 * q], d01);
      m2[2 * q + 1] = __builtin_elementwise_min(m2[2 * q + 1], d23);
    }
  }

  // ---- local T_sg = rank-17 of the 32 substream minima (>= seg's 17th item)
  unsigned mm[32];
#pragma unroll
  for (int j = 0; j < 16; ++j) {
    mm[2 * j]     = __float_as_uint(m2[j].x);
    mm[2 * j + 1] = __float_as_uint(m2[j].y);
  }
  unsigned s17[17], cm;
#pragma unroll
  for (int j = 0; j < 17; ++j) s17[j] = mm[j];
  cm = s17[0];
#pragma unroll
  for (int j = 1; j < 17; ++j) cm = (s17[j] > cm) ? s17[j] : cm;
#pragma unroll
  for (int j = 17; j < 32; ++j) insN<17>(mm[j], s17, cm);

  // ---- point threshold T* = min over the point's 8 segments (lane bits 3..5).
  //      Valid: minimizing segment alone has >=17 items <= T* => T* >= point's
  //      17th-smallest item (incl self) >= 16th non-self NN distance.
  unsigned tl = cm;
  {
    unsigned o;
    o = (unsigned)__shfl_xor((int)tl, 8, 64);  tl = (o < tl) ? o : tl;
    o = (unsigned)__shfl_xor((int)tl, 16, 64); tl = (o < tl) ? o : tl;
    o = (unsigned)__shfl_xor((int)tl, 32, 64); tl = (o < tl) ? o : tl;
  }
  const float Tval = __uint_as_float(tl);

  __syncthreads();  // pcnt zeroing visible before any atomic

  // ---- pass 2: collect all d <= T* into the point's compact LDS list
  //      (E ~18 items per POINT total; ds_add_rtn gives the slot)
#pragma unroll 1
  for (int t0 = 0; t0 < SEG / 4; t0 += 8) {
#pragma unroll
    for (int q = 0; q < 8; ++q) {
      const float* qb = cp + (size_t)(t0 + q) * 12;
      const float4 X = *(const float4*)(qb + 0);
      const float4 Y = *(const float4*)(qb + 4);
      const float4 Z = *(const float4*)(qb + 8);
      f32x2 x01; x01.x = X.x; x01.y = X.y;
      f32x2 x23; x23.x = X.z; x23.y = X.w;
      f32x2 y01; y01.x = Y.x; y01.y = Y.y;
      f32x2 y23; y23.x = Y.z; y23.y = Y.w;
      f32x2 z01; z01.x = Z.x; z01.y = Z.y;
      f32x2 z23; z23.x = Z.z; z23.y = Z.w;
      const f32x2 dx0 = x01 - vx, dy0 = y01 - vy, dz0 = z01 - vz;
      const f32x2 dx1 = x23 - vx, dy1 = y23 - vy, dz1 = z23 - vz;
      const f32x2 d01 = dx0 * dx0 + dy0 * dy0 + dz0 * dz0;
      const f32x2 d23 = dx1 * dx1 + dy1 * dy1 + dz1 * dz1;
      const unsigned ib = (unsigned)(c0 + 4 * (t0 + q));
      if (d01.x <= Tval) {
        const unsigned slot = atomicAdd(&pcnt[pt], 1u);
        if (slot < (unsigned)CAPP)
          pbuf[pt * CAPP + slot] = (__float_as_uint(d01.x) & 0xFFFFF000u) | ib;
      }
      if (d01.y <= Tval) {
        const unsigned slot = atomicAdd(&pcnt[pt], 1u);
        if (slot < (unsigned)CAPP)
          pbuf[pt * CAPP + slot] = (__float_as_uint(d01.y) & 0xFFFFF000u) | (ib + 1);
      }
      if (d23.x <= Tval) {
        const unsigned slot = atomicAdd(&pcnt[pt], 1u);
        if (slot < (unsigned)CAPP)
          pbuf[pt * CAPP + slot] = (__float_as_uint(d23.x) & 0xFFFFF000u) | (ib + 2);
      }
      if (d23.y <= Tval) {
        const unsigned slot = atomicAdd(&pcnt[pt], 1u);
        if (slot < (unsigned)CAPP)
          pbuf[pt * CAPP + slot] = (__float_as_uint(d23.y) & 0xFFFFF000u) | (ib + 3);
      }
    }
  }
  __syncthreads();

  // ---- merge per point (threads 0..31), cov, store
  if (tid < PPB) {
    const int pm = chunk * PPB + tid;
    const unsigned selfk = (unsigned)pm;  // self: d==+0 -> key = index
    unsigned s16[16], cm16 = UMAX;
#pragma unroll
    for (int j = 0; j < 16; ++j) s16[j] = UMAX;

    const unsigned nraw = pcnt[tid];
    if (nraw <= (unsigned)CAPP) {
      for (unsigned j = 0; j < nraw; ++j) {
        unsigned kb = pbuf[tid * CAPP + j];
        kb = (kb == selfk) ? UMAX : kb;
        insN<16>(kb, s16, cm16);
      }
    } else {
      // overflow fallback (astronomically rare): exact full rescan
      const float qx0 = px, qy0 = py, qz0 = pz;  // NOTE: px of THIS thread's pt
      // recompute own coords for pm (tid-based, not pt-based)
      const float* mpq = wc + (size_t)(pm >> 2) * 12;
      const int peq = pm & 3;
      const float ax = mpq[0 + peq], ay = mpq[4 + peq], az = mpq[8 + peq];
      (void)qx0; (void)qy0; (void)qz0;
      for (int ci = 0; ci < PTS; ++ci) {
        const float* qb = wc + (size_t)(ci >> 2) * 12;
        const int e = ci & 3;
        const float dx = qb[e] - ax, dy = qb[4 + e] - ay, dz = qb[8 + e] - az;
        const float d  = fmaf(dz, dz, fmaf(dy, dy, dx * dx));
        unsigned kb = (__float_as_uint(d) & 0xFFFFF000u) | (unsigned)ci;
        kb = (ci == pm) ? UMAX : kb;
        insN<16>(kb, s16, cm16);
      }
    }

    float Sx = 0, Sy = 0, Sz = 0;
    float Sxx = 0, Sxy = 0, Sxz = 0, Syy = 0, Syz = 0, Szz = 0;
#pragma unroll
    for (int j = 0; j < 16; ++j) {
      const int idx = (int)(s16[j] & 0xFFFu);
      const float* qb = wc + (size_t)(idx >> 2) * 12;
      const int e = idx & 3;
      const float nx = qb[e], ny = qb[4 + e], nz = qb[8 + e];
      Sx += nx; Sy += ny; Sz += nz;
      Sxx = fmaf(nx, nx, Sxx); Sxy = fmaf(nx, ny, Sxy); Sxz = fmaf(nx, nz, Sxz);
      Syy = fmaf(ny, ny, Syy); Syz = fmaf(ny, nz, Syz); Szz = fmaf(nz, nz, Szz);
    }
    const float sc = 0.0625f;
    const float mx = Sx * sc, my = Sy * sc, mz = Sz * sc;
    const float cxx = fmaf(-mx, mx, Sxx * sc);
    const float cxy = fmaf(-mx, my, Sxy * sc);
    const float cxz = fmaf(-mx, mz, Sxz * sc);
    const float cyy = fmaf(-my, my, Syy * sc);
    const float cyz = fmaf(-my, mz, Syz * sc);
    const float czz = fmaf(-mz, mz, Szz * sc);

    const float* ob = wc + (size_t)(pm >> 2) * 12;
    const int oe = pm & 3;
    const int gid = cloud * PTS + pm;
    float4* o4 = (float4*)(out + (size_t)gid * 12);
    o4[0] = make_float4(ob[oe], ob[4 + oe], ob[8 + oe], cxx);
    o4[1] = make_float4(cxy, cxz, cxy, cyy);
    o4[2] = make_float4(cyz, cxz, cyz, czz);
  }
}

// ---- r3-proven AoS fallback (only if ws too small) ----
#define QTRF   1024
#define CAPF   36
__global__ __launch_bounds__(256, 4) void knn_cov_aos(const float* __restrict__ x,
                                                      float* __restrict__ out) {
  __shared__ unsigned scol[CAPF * 256];
  __shared__ unsigned scnt[256];

  const int tid  = threadIdx.x;
  const int lane = tid & 63;
  const int h     = __builtin_amdgcn_readfirstlane(tid >> 6);
  const int cloud = blockIdx.x >> 6;
  const int chunk = blockIdx.x & 63;
  const int p     = chunk * 64 + lane;

  const float* __restrict__ xc = x + (size_t)cloud * PTS * 3;
  const float px = xc[p * 3 + 0], py = xc[p * 3 + 1], pz = xc[p * 3 + 2];
  const int c0 = h * QTRF;
  const float* __restrict__ cc = xc + (size_t)c0 * 3;

  float m[64];
#pragma unroll
  for (int j = 0; j < 64; ++j) m[j] = 3.4e38f;
  for (int t0 = 0; t0 < QTRF; t0 += 64) {
#pragma unroll
    for (int g = 0; g < 8; ++g) {
#pragma unroll
      for (int j = 0; j < 8; ++j) {
        const int ci = t0 + g * 8 + j;
        const float dx = cc[ci * 3 + 0] - px, dy = cc[ci * 3 + 1] - py,
                    dz = cc[ci * 3 + 2] - pz;
        const float d = fmaf(dz, dz, fmaf(dy, dy, dx * dx));
        const int mi = g * 8 + j;
        m[mi] = fminf(m[mi], d);
      }
    }
  }
  unsigned s17[17], cm;
#pragma unroll
  for (int j = 0; j < 17; ++j) s17[j] = __float_as_uint(m[j]);
  cm = s17[0];
#pragma unroll
  for (int j = 1; j < 17; ++j) cm = (s17[j] > cm) ? s17[j] : cm;
#pragma unroll
  for (int j = 17; j < 64; ++j) insN<17>(__float_as_uint(m[j]), s17, cm);
  const float Tval = __uint_as_float(cm);

  unsigned cnt = 0;
  for (int t0 = 0; t0 < QTRF; t0 += 8) {
#pragma unroll
    for (int j = 0; j < 8; ++j) {
      const int ci = t0 + j;
      const float dx = cc[ci * 3 + 0] - px, dy = cc[ci * 3 + 1] - py,
                  dz = cc[ci * 3 + 2] - pz;
      const float d = fmaf(dz, dz, fmaf(dy, dy, dx * dx));
      if (d <= Tval) {
        const unsigned slot = (cnt < (unsigned)CAPF) ? cnt : (unsigned)(CAPF - 1);
        scol[slot * 256 + tid] =
            (__float_as_uint(d) & 0xFFFFF000u) | (unsigned)(c0 + ci);
        cnt++;
      }
    }
  }
  if (cnt > (unsigned)CAPF) {
    unsigned sf[17], cmf = UMAX;
#pragma unroll
    for (int j = 0; j < 17; ++j) sf[j] = UMAX;
    for (int ci = 0; ci < QTRF; ++ci) {
      const float dx = cc[ci * 3 + 0] - px, dy = cc[ci * 3 + 1] - py,
                  dz = cc[ci * 3 + 2] - pz;
      const float d = fmaf(dz, dz, fmaf(dy, dy, dx * dx));
      insN<17>((__float_as_uint(d) & 0xFFFFF000u) | (unsigned)(c0 + ci), sf, cmf);
    }
#pragma unroll
    for (int j = 0; j < 17; ++j) scol[j * 256 + tid] = sf[j];
    cnt = 17;
  }
  scnt[tid] = cnt;
  __syncthreads();

  if (tid < 64) {
    unsigned s16[16], cm16 = UMAX;
#pragma unroll
    for (int j = 0; j < 16; ++j) s16[j] = UMAX;
    const unsigned selfk = (unsigned)p;
#pragma unroll
    for (int k = 0; k < 4; ++k) {
      const int col = k * 64 + tid;
      const unsigned n = scnt[col];
      for (unsigned j = 0; j < n; ++j) {
        unsigned kb = scol[j * 256 + col];
        kb = (kb == selfk) ? UMAX : kb;
        insN<16>(kb, s16, cm16);
      }
    }
    float Sx = 0, Sy = 0, Sz = 0;
    float Sxx = 0, Sxy = 0, Sxz = 0, Syy = 0, Syz = 0, Szz = 0;
#pragma unroll
    for (int j = 0; j < 16; ++j) {
      const int idx = (int)(s16[j] & 0xFFFu);
      const float nx = xc[idx * 3 + 0], ny = xc[idx * 3 + 1], nz = xc[idx * 3 + 2];
      Sx += nx; Sy += ny; Sz += nz;
      Sxx = fmaf(nx, nx, Sxx); Sxy = fmaf(nx, ny, Sxy); Sxz = fmaf(nx, nz, Sxz);
      Syy = fmaf(ny, ny, Syy); Syz = fmaf(ny, nz, Syz); Szz = fmaf(nz, nz, Szz);
    }
    const float sc = 0.0625f;
    const float mx = Sx * sc, my = Sy * sc, mz = Sz * sc;
    const float cxx = fmaf(-mx, mx, Sxx * sc);
    const float cxy = fmaf(-mx, my, Sxy * sc);
    const float cxz = fmaf(-mx, mz, Sxz * sc);
    const float cyy = fmaf(-my, my, Syy * sc);
    const float cyz = fmaf(-my, mz, Syz * sc);
    const float czz = fmaf(-mz, mz, Szz * sc);

    const int gid = cloud * PTS + p;
    float4* o4 = (float4*)(out + (size_t)gid * 12);
    o4[0] = make_float4(px, py, pz, cxx);
    o4[1] = make_float4(cxy, cxz, cxy, cyy);
    o4[2] = make_float4(cyz, cxz, cyz, czz);
  }
}

extern "C" void kernel_launch(void* const* d_in, const int* in_sizes, int n_in,
                              void* d_out, int out_size, void* d_ws, size_t ws_size,
                              hipStream_t stream) {
  const float* x = (const float*)d_in[0];
  float* out = (float*)d_out;
  if (ws_size >= (size_t)NQUADS * 12 * sizeof(float)) {
    float* ws = (float*)d_ws;
    quad_pack<<<NQUADS / TPB, TPB, 0, stream>>>(x, ws);
    knn_cov_c<<<dim3(NCLOUD * (PTS / PPB)), TPB, 0, stream>>>(ws, out);  // 2048
  } else {
    knn_cov_aos<<<dim3(NCLOUD * 64), 256, 0, stream>>>(x, out);
  }
}

// Round 11
// 201.817 us; speedup vs baseline: 5.8258x; 5.8258x over previous
//
#include <hip/hip_runtime.h>

#define PTS    4096
#define TPB    256
#define PPB    64      // points per block (one per lane of the merge wave)
#define QTR    1024    // candidates scanned per thread (4-way split)
#define NSUB   64      // substream minima per thread (pass 1)
#define CAP    36      // collect slots per thread
#define NCLOUD 16
#define UMAX   0xFFFFFFFFu

// insert key into unsorted top-N (s holds the N smallest seen, cmax = max of s)
template<int N>
__device__ __forceinline__ void insN(unsigned key, unsigned (&s)[N], unsigned &cmax) {
  if (key < cmax) {
    bool done = false;
#pragma unroll
    for (int i = 0; i < N; ++i) {
      bool c = (!done) && (s[i] == cmax);
      s[i] = c ? key : s[i];
      done = done || c;
    }
    cmax = s[0];
#pragma unroll
    for (int i = 1; i < N; ++i) cmax = (s[i] > cmax) ? s[i] : cmax;
  }
}

__global__ __launch_bounds__(TPB, 4) void knn_cov(const float* __restrict__ x,
                                                  float* __restrict__ out) {
  __shared__ unsigned scol[CAP * TPB];  // 36 KB: per-thread collect columns
  __shared__ unsigned scnt[TPB];        // 1 KB  (total ~37 KB -> 4 blocks/CU)

  const int tid  = threadIdx.x;
  const int lane = tid & 63;
  // wave id: uniform by construction; readfirstlane makes the compiler see it
  // as uniform so candidate loads can go to the scalar (SMEM) path.
  const int h     = __builtin_amdgcn_readfirstlane(tid >> 6);
  const int cloud = blockIdx.x >> 6;          // 64 chunks per cloud
  const int chunk = blockIdx.x & 63;
  const int p     = chunk * PPB + lane;       // in-cloud point for this lane

  const float* __restrict__ xc = x + (size_t)cloud * PTS * 3;

  const float px = xc[p * 3 + 0];
  const float py = xc[p * 3 + 1];
  const float pz = xc[p * 3 + 2];

  const int c0 = h * QTR;                     // this wave's candidate quarter
  const float* __restrict__ cc = xc + (size_t)c0 * 3;

  // ---- pass 1: 64 substream minima, diff-form distance (7 VALU/cand, no DS)
  float m[NSUB];
#pragma unroll
  for (int j = 0; j < NSUB; ++j) m[j] = 3.4e38f;
  for (int t0 = 0; t0 < QTR; t0 += NSUB) {
#pragma unroll
    for (int g = 0; g < NSUB / 8; ++g) {
#pragma unroll
      for (int j = 0; j < 8; ++j) {
        const int ci = t0 + g * 8 + j;
        const float qx = cc[ci * 3 + 0];
        const float qy = cc[ci * 3 + 1];
        const float qz = cc[ci * 3 + 2];
        const float dx = qx - px, dy = qy - py, dz = qz - pz;
        const float d  = fmaf(dz, dz, fmaf(dy, dy, dx * dx));
        const int mi   = g * 8 + j;           // static index
        m[mi] = fminf(m[mi], d);
      }
    }
  }

  // ---- threshold = 17th smallest of 64 minima (rank 17 absorbs self d=0;
  //      >= true 16th-smallest real distance of this quarter)
  unsigned s17[17], cm;
#pragma unroll
  for (int j = 0; j < 17; ++j) s17[j] = __float_as_uint(m[j]);
  cm = s17[0];
#pragma unroll
  for (int j = 1; j < 17; ++j) cm = (s17[j] > cm) ? s17[j] : cm;
#pragma unroll
  for (int j = 17; j < NSUB; ++j) insN<17>(__float_as_uint(m[j]), s17, cm);
  const float Tval = __uint_as_float(cm);

  // ---- pass 2: collect all d <= T into LDS columns (clamped slot, no branch
  //      inside the event block beyond the event itself)
  unsigned cnt = 0;
  for (int t0 = 0; t0 < QTR; t0 += 8) {
#pragma unroll
    for (int j = 0; j < 8; ++j) {
      const int ci = t0 + j;
      const float qx = cc[ci * 3 + 0];
      const float qy = cc[ci * 3 + 1];
      const float qz = cc[ci * 3 + 2];
      const float dx = qx - px, dy = qy - py, dz = qz - pz;
      const float d  = fmaf(dz, dz, fmaf(dy, dy, dx * dx));
      if (d <= Tval) {
        const unsigned slot = (cnt < (unsigned)CAP) ? cnt : (unsigned)(CAP - 1);
        scol[slot * TPB + tid] =
            (__float_as_uint(d) & 0xFFFFF000u) | (unsigned)(c0 + ci);
        cnt++;
      }
    }
  }

  // ---- overflow fallback (rare): exact top-17 rescan of this quarter
  if (cnt > (unsigned)CAP) {
    unsigned sf[17], cmf = UMAX;
#pragma unroll
    for (int j = 0; j < 17; ++j) sf[j] = UMAX;
#pragma unroll 4
    for (int ci = 0; ci < QTR; ++ci) {
      const float qx = cc[ci * 3 + 0];
      const float qy = cc[ci * 3 + 1];
      const float qz = cc[ci * 3 + 2];
      const float dx = qx - px, dy = qy - py, dz = qz - pz;
      const float d  = fmaf(dz, dz, fmaf(dy, dy, dx * dx));
      const unsigned kb = (__float_as_uint(d) & 0xFFFFF000u) | (unsigned)(c0 + ci);
      insN<17>(kb, sf, cmf);
    }
#pragma unroll
    for (int j = 0; j < 17; ++j) scol[j * TPB + tid] = sf[j];
    cnt = 17;
  }
  scnt[tid] = cnt;
  __syncthreads();

  // ---- merge the 4 quarters' candidate sets (wave 0), cov, store
  if (tid < PPB) {
    unsigned s16[16], cm16 = UMAX;
#pragma unroll
    for (int j = 0; j < 16; ++j) s16[j] = UMAX;
    const unsigned selfk = (unsigned)p;  // self: d==+0 exactly -> key = index
#pragma unroll
    for (int k = 0; k < 4; ++k) {
      const int col = k * PPB + tid;
      const unsigned n = scnt[col];
      unsigned w = n;
#pragma unroll
      for (int off = 32; off >= 1; off >>= 1) {
        unsigned o = (unsigned)__shfl_xor((int)w, off, 64);
        w = (o > w) ? o : w;
      }
      for (unsigned j = 0; j < w; ++j) {
        unsigned kb = (j < n) ? scol[j * TPB + col] : UMAX;
        kb = (kb == selfk) ? UMAX : kb;
        insN<16>(kb, s16, cm16);
      }
    }

    // gather neighbor coords (L1/L2-resident), raw moments -> covariance
    float Sx = 0, Sy = 0, Sz = 0;
    float Sxx = 0, Sxy = 0, Sxz = 0, Syy = 0, Syz = 0, Szz = 0;
#pragma unroll
    for (int j = 0; j < 16; ++j) {
      const int idx = (int)(s16[j] & 0xFFFu);
      const float nx = xc[idx * 3 + 0];
      const float ny = xc[idx * 3 + 1];
      const float nz = xc[idx * 3 + 2];
      Sx += nx; Sy += ny; Sz += nz;
      Sxx = fmaf(nx, nx, Sxx); Sxy = fmaf(nx, ny, Sxy); Sxz = fmaf(nx, nz, Sxz);
      Syy = fmaf(ny, ny, Syy); Syz = fmaf(ny, nz, Syz); Szz = fmaf(nz, nz, Szz);
    }
    const float sc = 0.0625f;
    const float mx = Sx * sc, my = Sy * sc, mz = Sz * sc;
    const float cxx = fmaf(-mx, mx, Sxx * sc);
    const float cxy = fmaf(-mx, my, Sxy * sc);
    const float cxz = fmaf(-mx, mz, Sxz * sc);
    const float cyy = fmaf(-my, my, Syy * sc);
    const float cyz = fmaf(-my, mz, Syz * sc);
    const float czz = fmaf(-mz, mz, Szz * sc);

    const int gid = cloud * PTS + p;
    float4* o4 = (float4*)(out + (size_t)gid * 12);
    o4[0] = make_float4(px, py, pz, cxx);
    o4[1] = make_float4(cxy, cxz, cxy, cyy);
    o4[2] = make_float4(cyz, cxz, cyz, czz);
  }
}

extern "C" void kernel_launch(void* const* d_in, const int* in_sizes, int n_in,
                              void* d_out, int out_size, void* d_ws, size_t ws_size,
                              hipStream_t stream) {
  const float* x = (const float*)d_in[0];
  float* out = (float*)d_out;
  dim3 grid(NCLOUD * (PTS / PPB));  // 16 clouds x 64 chunks = 1024 blocks = 4/CU
  knn_cov<<<grid, TPB, 0, stream>>>(x, out);
}